// Round 4
// baseline (520.122 us; speedup 1.0000x reference)
//
#include <hip/hip_runtime.h>

// MultiHeadAttentionLayer on MI355X (gfx950).
// B=4, S=2048, D=1024, H=16, Dh=64. All-bf16 MFMA pipeline:
//   wtrans:   Wt[n][k] = bf16(W[k][n])               (4 weights)
//   gemm_qkv: Qp/Kp [B,H,S,64] bf16 (Q pre-scaled by 0.125*log2e), Vtg [B,H,64,S]
//   attn:     flash attention, swapped-operand 32x32x16 MFMA, exp2-domain softmax,
//             NO LDS / NO barriers: K,V fragments direct from global (L2-resident)
//   gemm_out: ctx @ Wo^T + bo -> fp32 d_out

typedef float  f32x4  __attribute__((ext_vector_type(4)));
typedef float  f32x16 __attribute__((ext_vector_type(16)));
typedef short  s16x8  __attribute__((ext_vector_type(8)));
typedef unsigned short u16x4 __attribute__((ext_vector_type(4)));

#define DEV static __device__ __forceinline__

DEV unsigned short f2bf(float f) {            // RNE f32 -> bf16 (scalar)
  unsigned u = __float_as_uint(f);
  u += 0x7fffu + ((u >> 16) & 1u);
  return (unsigned short)(u >> 16);
}

DEV unsigned cvtpk(float lo, float hi) {      // word.lo=bf16(lo), word.hi=bf16(hi)
  unsigned r;
  asm("v_cvt_pk_bf16_f32 %0, %1, %2" : "=v"(r) : "v"(lo), "v"(hi));
  return r;
}

DEV void gld_lds16(const void* g, void* l) {  // async global->LDS, 16B/lane
  __builtin_amdgcn_global_load_lds(
      (const __attribute__((address_space(1))) unsigned int*)g,
      (__attribute__((address_space(3))) unsigned int*)l, 16, 0, 0);
}

// ---------------------------------------------------------------- wtrans ----
__global__ __launch_bounds__(256) void wtrans_kernel(
    const float* __restrict__ W0, const float* __restrict__ W1,
    const float* __restrict__ W2, const float* __restrict__ W3,
    unsigned short* __restrict__ T0, unsigned short* __restrict__ T1,
    unsigned short* __restrict__ T2, unsigned short* __restrict__ T3)
{
  __shared__ float tile[64][65];
  const float* W; unsigned short* T;
  switch (blockIdx.z) {
    case 0: W = W0; T = T0; break;
    case 1: W = W1; T = T1; break;
    case 2: W = W2; T = T2; break;
    default: W = W3; T = T3; break;
  }
  const int bi = blockIdx.x, bj = blockIdx.y;
  const int t = threadIdx.x;
  const int c4 = (t & 15) * 4, rr = t >> 4;
  #pragma unroll
  for (int j = 0; j < 4; j++) {
    int r = j * 16 + rr;
    float4 v = *(const float4*)(W + (size_t)(bi * 64 + r) * 1024 + bj * 64 + c4);
    tile[r][c4 + 0] = v.x; tile[r][c4 + 1] = v.y;
    tile[r][c4 + 2] = v.z; tile[r][c4 + 3] = v.w;
  }
  __syncthreads();
  #pragma unroll
  for (int j = 0; j < 4; j++) {
    int n = j * 16 + rr;
    uint2 p;
    p.x = cvtpk(tile[c4 + 0][n], tile[c4 + 1][n]);
    p.y = cvtpk(tile[c4 + 2][n], tile[c4 + 3][n]);
    *(uint2*)(T + (size_t)(bj * 64 + n) * 1024 + bi * 64 + c4) = p;
  }
}

// -------------------------------------------------------------- gemm_qkv ----
// C = A(f32,[8192x1024]) @ Wt^T + bias; 128x128 tile, BK=32, 4 waves (2x2).
__global__ __launch_bounds__(256) void gemm_qkv_kernel(
    const float* __restrict__ Aq, const float* __restrict__ Ak, const float* __restrict__ Av,
    const unsigned short* __restrict__ Btq, const unsigned short* __restrict__ Btk,
    const unsigned short* __restrict__ Btv,
    const float* __restrict__ pbq, const float* __restrict__ pbk, const float* __restrict__ pbv,
    unsigned short* __restrict__ Qp, unsigned short* __restrict__ Kp,
    unsigned short* __restrict__ Vtg)
{
  const int z = blockIdx.z;
  const float* A  = (z == 0) ? Aq : (z == 1) ? Ak : Av;
  const unsigned short* Bt = (z == 0) ? Btq : (z == 1) ? Btk : Btv;
  const float* bias = (z == 0) ? pbq : (z == 1) ? pbk : pbv;
  unsigned short* outp = (z == 0) ? Qp : (z == 1) ? Kp : Vtg;
  const float scale = (z == 0) ? 0.18033688011112042f : 1.0f;  // 0.125*log2(e)
  const int epi = (z == 2) ? 1 : 0;

  const int tid = threadIdx.x;
  const int lane = tid & 63, w = tid >> 6;
  const int wm = w >> 1, wn = w & 1;
  // XCD-aware swizzle: nwg=512 per z, 64-block contiguous chunk per XCD.
  const int H = blockIdx.y * 8 + blockIdx.x;
  const int L = (H & 7) * 64 + (H >> 3);
  const int m0 = (L >> 3) * 128, n0 = (L & 7) * 128;
  __shared__ __align__(16) char sA[8192];
  __shared__ __align__(16) char sB[8192];

  f32x4 acc[4][4];
  #pragma unroll
  for (int i = 0; i < 4; i++)
    #pragma unroll
    for (int j = 0; j < 4; j++)
      #pragma unroll
      for (int r = 0; r < 4; r++) acc[i][j][r] = 0.f;

  const int arow = tid >> 3;             // A staging: rows 0..31 (+32j)
  const int akl  = (tid & 7) * 4;
  const int brow = lane >> 2;            // B staging within 16-row chunk
  const int bkl  = (lane & 3) * 8;

  for (int kt = 0; kt < 32; kt++) {
    const int k0 = kt * 32;
    #pragma unroll
    for (int j = 0; j < 4; j++) {        // A: f32 -> bf16 reg staging via cvt_pk
      int row = arow + j * 32;
      float4 v = *(const float4*)(A + (size_t)(m0 + row) * 1024 + k0 + akl);
      uint2 p; p.x = cvtpk(v.x, v.y); p.y = cvtpk(v.z, v.w);
      *(uint2*)(sA + row * 64 + akl * 2) = p;
    }
    #pragma unroll
    for (int j = 0; j < 2; j++) {        // B: async global->LDS
      int row = (w * 2 + j) * 16 + brow;
      gld_lds16(Bt + (size_t)(n0 + row) * 1024 + k0 + bkl, sB + (w * 2 + j) * 1024);
    }
    __syncthreads();
    s16x8 aF[4], bF[4];
    #pragma unroll
    for (int i = 0; i < 4; i++)
      aF[i] = *(const s16x8*)(sA + (wm * 64 + i * 16 + (lane & 15)) * 64 + (lane >> 4) * 16);
    #pragma unroll
    for (int i = 0; i < 4; i++)
      bF[i] = *(const s16x8*)(sB + (wn * 64 + i * 16 + (lane & 15)) * 64 + (lane >> 4) * 16);
    #pragma unroll
    for (int mi = 0; mi < 4; mi++)
      #pragma unroll
      for (int ni = 0; ni < 4; ni++)
        acc[mi][ni] = __builtin_amdgcn_mfma_f32_16x16x32_bf16(aF[mi], bF[ni], acc[mi][ni], 0, 0, 0);
    __syncthreads();
  }

  #pragma unroll
  for (int ni = 0; ni < 4; ni++) {
    const int gn = n0 + wn * 64 + ni * 16 + (lane & 15);
    const float bval = bias[gn];
    const int h_ = gn >> 6, d_ = gn & 63;
    #pragma unroll
    for (int mi = 0; mi < 4; mi++) {
      const int gm = m0 + wm * 64 + mi * 16 + (lane >> 4) * 4;
      const int b_ = gm >> 11, s_ = gm & 2047;
      f32x4 a = acc[mi][ni];
      if (epi == 0) {                    // [B,H,S,64] bf16 (Q pre-scaled)
        #pragma unroll
        for (int r = 0; r < 4; r++)
          outp[((size_t)(b_ * 16 + h_) * 2048 + (s_ + r)) * 64 + d_] =
              f2bf((a[r] + bval) * scale);
      } else {                           // V^T: [B,H,64,S] bf16, 4 consecutive s
        uint2 p;
        p.x = cvtpk(a[0] + bval, a[1] + bval);
        p.y = cvtpk(a[2] + bval, a[3] + bval);
        *(uint2*)(outp + ((size_t)(b_ * 16 + h_) * 64 + d_) * 2048 + s_) = p;
      }
    }
  }
}

// ------------------------------------------------------------------ attn ----
// Swapped-operand flash attention, NO LDS / NO barriers. Per block: 4 fully
// independent waves x 32 q-rows; KV tile 64. K/V MFMA fragments loaded directly
// from global (KV is L2-resident: 256 KB/head, FETCH_SIZE confirmed 25 MB).
// scores^T = mfma(K, Q); O^T = mfma(Vt, P^T); softmax fully in-lane.
__global__ __launch_bounds__(256) void attn_kernel(
    const unsigned short* __restrict__ Qp, const unsigned short* __restrict__ Kp,
    const unsigned short* __restrict__ Vtg, const int* __restrict__ mask,
    unsigned short* __restrict__ ctx)
{
  constexpr int S = 2048;
  const int tid = threadIdx.x;
  const int lane = tid & 63, w = tid >> 6;
  const int hi = lane >> 5, q31 = lane & 31;
  // XCD swizzle: 1024 blocks, 128/XCD -> 8 heads per XCD (KV L2-resident).
  const int H = blockIdx.y * 16 + blockIdx.x;
  const int L = (H & 7) * 128 + (H >> 3);
  const int qb = L & 15, bh = L >> 4;
  const int b = bh >> 4, h = bh & 15;
  const int q0 = qb * 128;

  const int qrow = q0 + w * 32 + q31;
  const unsigned short* qptr = Qp + ((size_t)bh * S + qrow) * 64;
  s16x8 qf[4];
  #pragma unroll
  for (int ks = 0; ks < 4; ks++) qf[ks] = *(const s16x8*)(qptr + ks * 16 + hi * 8);

  // per-lane fragment bases (same elements the swizzled-LDS path produced)
  const unsigned short* kb = Kp  + (size_t)bh * S * 64 + q31 * 64 + hi * 8;
  const unsigned short* vb = Vtg + (size_t)bh * 64 * S + q31 * S + hi * 8;

  f32x16 o[2];
  #pragma unroll
  for (int d = 0; d < 2; d++)
    #pragma unroll
    for (int i = 0; i < 16; i++) o[d][i] = 0.f;
  float m_run = -1e30f, l_run = 0.f;

  // hoisted mask check: one wave-uniform flag for the all-ones fast path
  const int* mrow = mask + b * S;
  bool all1 = true;
  for (int t = 0; t < 32; t++) all1 &= (mrow[t * 64 + lane] != 0);
  const bool fullmask = (__ballot(all1) == ~0ull);

  for (int t = 0; t < 32; t++) {
    const int kv0 = t * 64;

    // QK^T (swapped): sc[kvf] covers kv in [kv0+32*kvf, +32)
    f32x16 sc[2];
    #pragma unroll
    for (int kvf = 0; kvf < 2; kvf++)
      #pragma unroll
      for (int i = 0; i < 16; i++) sc[kvf][i] = 0.f;

    __builtin_amdgcn_s_setprio(1);
    #pragma unroll
    for (int kvf = 0; kvf < 2; kvf++) {
      const unsigned short* kr = kb + (size_t)(kv0 + kvf * 32) * 64;
      #pragma unroll
      for (int ks = 0; ks < 4; ks++) {
        s16x8 kfr = *(const s16x8*)(kr + ks * 16);
        sc[kvf] = __builtin_amdgcn_mfma_f32_32x32x16_bf16(kfr, qf[ks], sc[kvf], 0, 0, 0);
      }
    }
    __builtin_amdgcn_s_setprio(0);

    if (!fullmask) {
      const unsigned long long mv = __ballot(mrow[kv0 + lane] != 0);
      if (mv != ~0ull) {
        #pragma unroll
        for (int kvf = 0; kvf < 2; kvf++)
          #pragma unroll
          for (int r = 0; r < 16; r++) {
            int kvp = kvf * 32 + (r & 3) + 8 * (r >> 2) + 4 * hi;
            if (!((mv >> kvp) & 1ull)) sc[kvf][r] = -1e30f;
          }
      }
    }

    // row max (4 parallel chains), cross-half via shfl (proven path)
    float mx[4] = {-1e30f, -1e30f, -1e30f, -1e30f};
    #pragma unroll
    for (int kvf = 0; kvf < 2; kvf++)
      #pragma unroll
      for (int r = 0; r < 16; r++) mx[r & 3] = fmaxf(mx[r & 3], sc[kvf][r]);
    float mloc = fmaxf(fmaxf(mx[0], mx[1]), fmaxf(mx[2], mx[3]));
    mloc = fmaxf(mloc, __shfl_xor(mloc, 32));

    // unconditional online-softmax rescale (proven numerics)
    const float mnew = fmaxf(m_run, mloc);
    const float alpha = __builtin_amdgcn_exp2f(m_run - mnew);
    m_run = mnew;
    #pragma unroll
    for (int d = 0; d < 2; d++)
      #pragma unroll
      for (int i = 0; i < 16; i++) o[d][i] *= alpha;

    float ps[4] = {0.f, 0.f, 0.f, 0.f};
    #pragma unroll
    for (int kvf = 0; kvf < 2; kvf++)
      #pragma unroll
      for (int r = 0; r < 16; r++) {
        float p = __builtin_amdgcn_exp2f(sc[kvf][r] - m_run);
        sc[kvf][r] = p;
        ps[r & 3] += p;
      }
    float psum = (ps[0] + ps[1]) + (ps[2] + ps[3]);
    psum += __shfl_xor(psum, 32);
    l_run = l_run * alpha + psum;

    // pack P -> bf16 via cvt_pk; cross-half exchange via shfl_xor (proven path)
    s16x8 pa[4];
    #pragma unroll
    for (int ks = 0; ks < 4; ks++) {
      const int kvf = ks >> 1, base = (ks & 1) * 8;
      unsigned a0 = cvtpk(sc[kvf][base + 0], sc[kvf][base + 1]);
      unsigned a1 = cvtpk(sc[kvf][base + 2], sc[kvf][base + 3]);
      unsigned b0 = cvtpk(sc[kvf][base + 4], sc[kvf][base + 5]);
      unsigned b1 = cvtpk(sc[kvf][base + 6], sc[kvf][base + 7]);
      unsigned ax0 = __shfl_xor(a0, 32), ax1 = __shfl_xor(a1, 32);
      unsigned bx0 = __shfl_xor(b0, 32), bx1 = __shfl_xor(b1, 32);
      union { unsigned u[4]; s16x8 s; } cv;
      cv.u[0] = hi ? bx0 : a0;
      cv.u[1] = hi ? bx1 : a1;
      cv.u[2] = hi ? b0  : ax0;
      cv.u[3] = hi ? b1  : ax1;
      pa[ks] = cv.s;
    }

    // PV (swapped): o[df] += Vt_frag * P^T_frag
    __builtin_amdgcn_s_setprio(1);
    #pragma unroll
    for (int df = 0; df < 2; df++) {
      const unsigned short* vr = vb + (size_t)(df * 32) * S + kv0;
      #pragma unroll
      for (int ks = 0; ks < 4; ks++) {
        s16x8 vfr = *(const s16x8*)(vr + ks * 16);
        o[df] = __builtin_amdgcn_mfma_f32_32x32x16_bf16(vfr, pa[ks], o[df], 0, 0, 0);
      }
    }
    __builtin_amdgcn_s_setprio(0);
  }

  const float inv = 1.0f / l_run;
  unsigned short* cp = ctx + ((size_t)(b * S + qrow)) * 1024 + h * 64;
  #pragma unroll
  for (int df = 0; df < 2; df++)
    #pragma unroll
    for (int rq = 0; rq < 4; rq++) {
      uint2 pw;
      pw.x = cvtpk(o[df][rq * 4 + 0] * inv, o[df][rq * 4 + 1] * inv);
      pw.y = cvtpk(o[df][rq * 4 + 2] * inv, o[df][rq * 4 + 3] * inv);
      *(uint2*)(cp + df * 32 + rq * 8 + hi * 4) = pw;
    }
}

// -------------------------------------------------------------- gemm_out ----
__global__ __launch_bounds__(256) void gemm_out_kernel(
    const unsigned short* __restrict__ Actx, const unsigned short* __restrict__ Bt,
    const float* __restrict__ bias, float* __restrict__ outp)
{
  const int tid = threadIdx.x;
  const int lane = tid & 63, w = tid >> 6;
  const int wm = w >> 1, wn = w & 1;
  const int H = blockIdx.y * 8 + blockIdx.x;
  const int L = (H & 7) * 64 + (H >> 3);
  const int m0 = (L >> 3) * 128, n0 = (L & 7) * 128;
  __shared__ __align__(16) char sA[8192];
  __shared__ __align__(16) char sB[8192];

  f32x4 acc[4][4];
  #pragma unroll
  for (int i = 0; i < 4; i++)
    #pragma unroll
    for (int j = 0; j < 4; j++)
      #pragma unroll
      for (int r = 0; r < 4; r++) acc[i][j][r] = 0.f;

  const int brow = lane >> 2;
  const int bkl  = (lane & 3) * 8;

  for (int kt = 0; kt < 32; kt++) {
    const int k0 = kt * 32;
    #pragma unroll
    for (int j = 0; j < 2; j++) {
      int row = (w * 2 + j) * 16 + brow;
      gld_lds16(Actx + (size_t)(m0 + row) * 1024 + k0 + bkl, sA + (w * 2 + j) * 1024);
      gld_lds16(Bt   + (size_t)(n0 + row) * 1024 + k0 + bkl, sB + (w * 2 + j) * 1024);
    }
    __syncthreads();
    s16x8 aF[4], bF[4];
    #pragma unroll
    for (int i = 0; i < 4; i++)
      aF[i] = *(const s16x8*)(sA + (wm * 64 + i * 16 + (lane & 15)) * 64 + (lane >> 4) * 16);
    #pragma unroll
    for (int i = 0; i < 4; i++)
      bF[i] = *(const s16x8*)(sB + (wn * 64 + i * 16 + (lane & 15)) * 64 + (lane >> 4) * 16);
    #pragma unroll
    for (int mi = 0; mi < 4; mi++)
      #pragma unroll
      for (int ni = 0; ni < 4; ni++)
        acc[mi][ni] = __builtin_amdgcn_mfma_f32_16x16x32_bf16(aF[mi], bF[ni], acc[mi][ni], 0, 0, 0);
    __syncthreads();
  }

  #pragma unroll
  for (int ni = 0; ni < 4; ni++) {
    const int gn = n0 + wn * 64 + ni * 16 + (lane & 15);
    const float bval = bias[gn];
    #pragma unroll
    for (int mi = 0; mi < 4; mi++) {
      const int gm = m0 + wm * 64 + mi * 16 + (lane >> 4) * 4;
      #pragma unroll
      for (int r = 0; r < 4; r++)
        outp[(size_t)(gm + r) * 1024 + gn] = acc[mi][ni][r] + bval;
    }
  }
}

// ---------------------------------------------------------------- launch ----
extern "C" void kernel_launch(void* const* d_in, const int* in_sizes, int n_in,
                              void* d_out, int out_size, void* d_ws, size_t ws_size,
                              hipStream_t stream)
{
  const float* query = (const float*)d_in[0];
  const float* key_  = (const float*)d_in[1];
  const float* value = (const float*)d_in[2];
  const int*   mask  = (const int*)d_in[3];
  const float* Wq = (const float*)d_in[4];
  const float* bq = (const float*)d_in[5];
  const float* Wk = (const float*)d_in[6];
  const float* bk = (const float*)d_in[7];
  const float* Wv = (const float*)d_in[8];
  const float* bv = (const float*)d_in[9];
  const float* Wo = (const float*)d_in[10];
  const float* bo = (const float*)d_in[11];
  float* out = (float*)d_out;

  unsigned short* Wtq = (unsigned short*)d_ws;
  unsigned short* Wtk = Wtq + (1u << 20);
  unsigned short* Wtv = Wtk + (1u << 20);
  unsigned short* Wto = Wtv + (1u << 20);
  unsigned short* Qp  = Wto + (1u << 20);   // [B,H,S,64], pre-scaled by 0.125*log2e
  unsigned short* Kp  = Qp  + (8u << 20);   // [B,H,S,64]
  unsigned short* Vtg = Kp  + (8u << 20);   // [B,H,64,S]
  unsigned short* ctx = Vtg + (8u << 20);   // [B,S,1024]

  wtrans_kernel<<<dim3(16, 16, 4), 256, 0, stream>>>(Wq, Wk, Wv, Wo, Wtq, Wtk, Wtv, Wto);
  gemm_qkv_kernel<<<dim3(8, 64, 3), 256, 0, stream>>>(query, key_, value,
                                                      Wtq, Wtk, Wtv, bq, bk, bv,
                                                      Qp, Kp, Vtg);
  attn_kernel<<<dim3(16, 64), 256, 0, stream>>>(Qp, Kp, Vtg, mask, ctx);
  gemm_out_kernel<<<dim3(8, 64), 256, 0, stream>>>(ctx, Wto, bo, out);
}

// Round 5
// 390.174 us; speedup vs baseline: 1.3331x; 1.3331x over previous
//
#include <hip/hip_runtime.h>

// MultiHeadAttentionLayer on MI355X (gfx950).
// B=4, S=2048, D=1024, H=16, Dh=64. All-bf16 MFMA pipeline:
//   wtrans:   Wt[n][k] = bf16(W[k][n])               (4 weights)
//   a2b:      query/key/value f32 -> bf16 (one pass; avoids 8x f32 re-reads)
//   gemm_qkv: pure-bf16 m97 GEMM -> Qp/Kp [B,H,S,64] (Q pre-scaled), Vtg [B,H,64,S]
//   attn:     flash attention, swapped-operand 32x32x16 MFMA, exp2-domain softmax,
//             single-buffer LDS (VGPR<128 => 4 waves/SIMD), cvtpk pack + setprio
//   gemm_out: ctx @ Wo^T + bo -> fp32 d_out

typedef float  f32x4  __attribute__((ext_vector_type(4)));
typedef float  f32x16 __attribute__((ext_vector_type(16)));
typedef short  s16x8  __attribute__((ext_vector_type(8)));
typedef unsigned short u16x4 __attribute__((ext_vector_type(4)));

#define DEV static __device__ __forceinline__

DEV unsigned short f2bf(float f) {            // RNE f32 -> bf16 (scalar)
  unsigned u = __float_as_uint(f);
  u += 0x7fffu + ((u >> 16) & 1u);
  return (unsigned short)(u >> 16);
}

DEV unsigned cvtpk(float lo, float hi) {      // word.lo=bf16(lo), word.hi=bf16(hi)
  unsigned r;
  asm("v_cvt_pk_bf16_f32 %0, %1, %2" : "=v"(r) : "v"(lo), "v"(hi));
  return r;
}

DEV void gld_lds16(const void* g, void* l) {  // async global->LDS, 16B/lane
  __builtin_amdgcn_global_load_lds(
      (const __attribute__((address_space(1))) unsigned int*)g,
      (__attribute__((address_space(3))) unsigned int*)l, 16, 0, 0);
}

// ---------------------------------------------------------------- wtrans ----
__global__ __launch_bounds__(256) void wtrans_kernel(
    const float* __restrict__ W0, const float* __restrict__ W1,
    const float* __restrict__ W2, const float* __restrict__ W3,
    unsigned short* __restrict__ T0, unsigned short* __restrict__ T1,
    unsigned short* __restrict__ T2, unsigned short* __restrict__ T3)
{
  __shared__ float tile[64][65];
  const float* W; unsigned short* T;
  switch (blockIdx.z) {
    case 0: W = W0; T = T0; break;
    case 1: W = W1; T = T1; break;
    case 2: W = W2; T = T2; break;
    default: W = W3; T = T3; break;
  }
  const int bi = blockIdx.x, bj = blockIdx.y;
  const int t = threadIdx.x;
  const int c4 = (t & 15) * 4, rr = t >> 4;
  #pragma unroll
  for (int j = 0; j < 4; j++) {
    int r = j * 16 + rr;
    float4 v = *(const float4*)(W + (size_t)(bi * 64 + r) * 1024 + bj * 64 + c4);
    tile[r][c4 + 0] = v.x; tile[r][c4 + 1] = v.y;
    tile[r][c4 + 2] = v.z; tile[r][c4 + 3] = v.w;
  }
  __syncthreads();
  #pragma unroll
  for (int j = 0; j < 4; j++) {
    int n = j * 16 + rr;
    uint2 p;
    p.x = cvtpk(tile[c4 + 0][n], tile[c4 + 1][n]);
    p.y = cvtpk(tile[c4 + 2][n], tile[c4 + 3][n]);
    *(uint2*)(T + (size_t)(bj * 64 + n) * 1024 + bi * 64 + c4) = p;
  }
}

// ------------------------------------------------------------------- a2b ----
// f32 -> bf16 cast of the three activation matrices (8 elems/thread).
__global__ __launch_bounds__(256) void a2b_kernel(
    const float* __restrict__ Aq, const float* __restrict__ Ak,
    const float* __restrict__ Av, unsigned short* __restrict__ Xb)
{
  const int z = blockIdx.y;
  const float* src = (z == 0) ? Aq : (z == 1) ? Ak : Av;
  const size_t i = ((size_t)blockIdx.x * 256 + threadIdx.x) * 8;
  float4 v0 = *(const float4*)(src + i);
  float4 v1 = *(const float4*)(src + i + 4);
  uint4 p;
  p.x = cvtpk(v0.x, v0.y); p.y = cvtpk(v0.z, v0.w);
  p.z = cvtpk(v1.x, v1.y); p.w = cvtpk(v1.z, v1.w);
  *(uint4*)(Xb + (size_t)z * 8388608 + i) = p;
}

// -------------------------------------------------------------- gemm_qkv ----
// C = Xb(bf16,[8192x1024]) @ Wt^T + bias; 128x128 tile, BK=32, 4 waves (2x2).
// Pure-bf16 m97 structure: both operands via global_load_lds width-16.
__global__ __launch_bounds__(256) void gemm_qkv_kernel(
    const unsigned short* __restrict__ Xb,
    const unsigned short* __restrict__ Btq, const unsigned short* __restrict__ Btk,
    const unsigned short* __restrict__ Btv,
    const float* __restrict__ pbq, const float* __restrict__ pbk, const float* __restrict__ pbv,
    unsigned short* __restrict__ Qp, unsigned short* __restrict__ Kp,
    unsigned short* __restrict__ Vtg)
{
  const int z = blockIdx.z;
  const unsigned short* A = Xb + (size_t)z * 8388608;
  const unsigned short* Bt = (z == 0) ? Btq : (z == 1) ? Btk : Btv;
  const float* bias = (z == 0) ? pbq : (z == 1) ? pbk : pbv;
  unsigned short* outp = (z == 0) ? Qp : (z == 1) ? Kp : Vtg;
  const float scale = (z == 0) ? 0.18033688011112042f : 1.0f;  // 0.125*log2(e)
  const int epi = (z == 2) ? 1 : 0;

  const int tid = threadIdx.x;
  const int lane = tid & 63, w = tid >> 6;
  const int wm = w >> 1, wn = w & 1;
  // XCD-aware swizzle: nwg=512 per z, 64-block contiguous chunk per XCD.
  const int H = blockIdx.y * 8 + blockIdx.x;
  const int L = (H & 7) * 64 + (H >> 3);
  const int m0 = (L >> 3) * 128, n0 = (L & 7) * 128;
  __shared__ __align__(16) char sA[8192];
  __shared__ __align__(16) char sB[8192];

  f32x4 acc[4][4];
  #pragma unroll
  for (int i = 0; i < 4; i++)
    #pragma unroll
    for (int j = 0; j < 4; j++)
      #pragma unroll
      for (int r = 0; r < 4; r++) acc[i][j][r] = 0.f;

  const int brow = lane >> 2;            // staging within 16-row chunk
  const int bkl  = (lane & 3) * 8;

  for (int kt = 0; kt < 32; kt++) {
    const int k0 = kt * 32;
    #pragma unroll
    for (int j = 0; j < 2; j++) {
      int row = (w * 2 + j) * 16 + brow;
      gld_lds16(A  + (size_t)(m0 + row) * 1024 + k0 + bkl, sA + (w * 2 + j) * 1024);
      gld_lds16(Bt + (size_t)(n0 + row) * 1024 + k0 + bkl, sB + (w * 2 + j) * 1024);
    }
    __syncthreads();
    s16x8 aF[4], bF[4];
    #pragma unroll
    for (int i = 0; i < 4; i++)
      aF[i] = *(const s16x8*)(sA + (wm * 64 + i * 16 + (lane & 15)) * 64 + (lane >> 4) * 16);
    #pragma unroll
    for (int i = 0; i < 4; i++)
      bF[i] = *(const s16x8*)(sB + (wn * 64 + i * 16 + (lane & 15)) * 64 + (lane >> 4) * 16);
    #pragma unroll
    for (int mi = 0; mi < 4; mi++)
      #pragma unroll
      for (int ni = 0; ni < 4; ni++)
        acc[mi][ni] = __builtin_amdgcn_mfma_f32_16x16x32_bf16(aF[mi], bF[ni], acc[mi][ni], 0, 0, 0);
    __syncthreads();
  }

  #pragma unroll
  for (int ni = 0; ni < 4; ni++) {
    const int gn = n0 + wn * 64 + ni * 16 + (lane & 15);
    const float bval = bias[gn];
    const int h_ = gn >> 6, d_ = gn & 63;
    #pragma unroll
    for (int mi = 0; mi < 4; mi++) {
      const int gm = m0 + wm * 64 + mi * 16 + (lane >> 4) * 4;
      const int b_ = gm >> 11, s_ = gm & 2047;
      f32x4 a = acc[mi][ni];
      if (epi == 0) {                    // [B,H,S,64] bf16 (Q pre-scaled)
        #pragma unroll
        for (int r = 0; r < 4; r++)
          outp[((size_t)(b_ * 16 + h_) * 2048 + (s_ + r)) * 64 + d_] =
              f2bf((a[r] + bval) * scale);
      } else {                           // V^T: [B,H,64,S] bf16, 4 consecutive s
        uint2 p;
        p.x = cvtpk(a[0] + bval, a[1] + bval);
        p.y = cvtpk(a[2] + bval, a[3] + bval);
        *(uint2*)(outp + ((size_t)(b_ * 16 + h_) * 64 + d_) * 2048 + s_) = p;
      }
    }
  }
}

// ------------------------------------------------------------------ attn ----
// Swapped-operand flash attention. Per block: 4 waves x 32 q-rows, KV tile 64.
// Single-buffer LDS (16 KB, VGPR<128 => 4 waves/SIMD resident — the R1 regime),
// cvt_pk pack + shfl exchange, setprio, hoisted mask, XCD swizzle.
__global__ __launch_bounds__(256) void attn_kernel(
    const unsigned short* __restrict__ Qp, const unsigned short* __restrict__ Kp,
    const unsigned short* __restrict__ Vtg, const int* __restrict__ mask,
    unsigned short* __restrict__ ctx)
{
  constexpr int S = 2048;
  const int tid = threadIdx.x;
  const int lane = tid & 63, w = tid >> 6;
  const int hi = lane >> 5, q31 = lane & 31;
  // XCD swizzle: 1024 blocks, 128/XCD -> 8 heads per XCD (KV L2-resident).
  const int H = blockIdx.y * 16 + blockIdx.x;
  const int L = (H & 7) * 128 + (H >> 3);
  const int qb = L & 15, bh = L >> 4;
  const int b = bh >> 4, h = bh & 15;
  const int q0 = qb * 128;
  __shared__ __align__(16) char Ks[8192];   // [64 kv][128B], XOR-swizzled rows
  __shared__ __align__(16) char Vts[8192];  // [64 d ][128B], XOR-swizzled rows

  const int qrow = q0 + w * 32 + q31;
  const unsigned short* qptr = Qp + ((size_t)bh * S + qrow) * 64;
  s16x8 qf[4];
  #pragma unroll
  for (int ks = 0; ks < 4; ks++) qf[ks] = *(const s16x8*)(qptr + ks * 16 + hi * 8);

  f32x16 o[2];
  #pragma unroll
  for (int d = 0; d < 2; d++)
    #pragma unroll
    for (int i = 0; i < 16; i++) o[d][i] = 0.f;
  float m_run = -1e30f, l_run = 0.f;

  // hoisted mask check: one wave-uniform flag for the all-ones fast path
  const int* mrow = mask + b * S;
  bool all1 = true;
  for (int t = 0; t < 32; t++) all1 &= (mrow[t * 64 + lane] != 0);
  const bool fullmask = (__ballot(all1) == ~0ull);

  for (int t = 0; t < 32; t++) {
    const int kv0 = t * 64;
    #pragma unroll
    for (int j = 0; j < 2; j++) {        // stage K and V^T tiles (pre-swizzled src)
      const int cb = (w * 2 + j) * 1024;
      const int oo = cb + lane * 16;
      const int row = oo >> 7;
      const int c = oo & 127;
      const int srcc = (c ^ ((row & 7) << 4)) >> 1;
      gld_lds16(Kp  + ((size_t)bh * S  + kv0 + row) * 64 + srcc, Ks  + cb);
      gld_lds16(Vtg + ((size_t)bh * 64 + row) * S + kv0  + srcc, Vts + cb);
    }
    __syncthreads();

    // QK^T (swapped): sc[kvf] covers kv in [kv0+32*kvf, +32)
    f32x16 sc[2];
    #pragma unroll
    for (int kvf = 0; kvf < 2; kvf++)
      #pragma unroll
      for (int i = 0; i < 16; i++) sc[kvf][i] = 0.f;

    __builtin_amdgcn_s_setprio(1);
    #pragma unroll
    for (int kvf = 0; kvf < 2; kvf++) {
      const int krow = kvf * 32 + q31;
      const int sw = (krow & 7) << 4;
      #pragma unroll
      for (int ks = 0; ks < 4; ks++) {
        s16x8 kf = *(const s16x8*)(Ks + krow * 128 + ((ks * 32 + hi * 16) ^ sw));
        sc[kvf] = __builtin_amdgcn_mfma_f32_32x32x16_bf16(kf, qf[ks], sc[kvf], 0, 0, 0);
      }
    }
    __builtin_amdgcn_s_setprio(0);

    if (!fullmask) {
      const unsigned long long mv = __ballot(mrow[kv0 + lane] != 0);
      if (mv != ~0ull) {
        #pragma unroll
        for (int kvf = 0; kvf < 2; kvf++)
          #pragma unroll
          for (int r = 0; r < 16; r++) {
            int kvp = kvf * 32 + (r & 3) + 8 * (r >> 2) + 4 * hi;
            if (!((mv >> kvp) & 1ull)) sc[kvf][r] = -1e30f;
          }
      }
    }

    // row max (4 parallel chains), cross-half via shfl (proven path)
    float mx[4] = {-1e30f, -1e30f, -1e30f, -1e30f};
    #pragma unroll
    for (int kvf = 0; kvf < 2; kvf++)
      #pragma unroll
      for (int r = 0; r < 16; r++) mx[r & 3] = fmaxf(mx[r & 3], sc[kvf][r]);
    float mloc = fmaxf(fmaxf(mx[0], mx[1]), fmaxf(mx[2], mx[3]));
    mloc = fmaxf(mloc, __shfl_xor(mloc, 32));

    // unconditional online-softmax rescale (proven numerics)
    const float mnew = fmaxf(m_run, mloc);
    const float alpha = __builtin_amdgcn_exp2f(m_run - mnew);
    m_run = mnew;
    #pragma unroll
    for (int d = 0; d < 2; d++)
      #pragma unroll
      for (int i = 0; i < 16; i++) o[d][i] *= alpha;

    float ps[4] = {0.f, 0.f, 0.f, 0.f};
    #pragma unroll
    for (int kvf = 0; kvf < 2; kvf++)
      #pragma unroll
      for (int r = 0; r < 16; r++) {
        float p = __builtin_amdgcn_exp2f(sc[kvf][r] - m_run);
        sc[kvf][r] = p;
        ps[r & 3] += p;
      }
    float psum = (ps[0] + ps[1]) + (ps[2] + ps[3]);
    psum += __shfl_xor(psum, 32);
    l_run = l_run * alpha + psum;

    // pack P -> bf16 via cvt_pk; cross-half exchange via shfl_xor (proven path)
    s16x8 pa[4];
    #pragma unroll
    for (int ks = 0; ks < 4; ks++) {
      const int kvf = ks >> 1, base = (ks & 1) * 8;
      unsigned a0 = cvtpk(sc[kvf][base + 0], sc[kvf][base + 1]);
      unsigned a1 = cvtpk(sc[kvf][base + 2], sc[kvf][base + 3]);
      unsigned b0 = cvtpk(sc[kvf][base + 4], sc[kvf][base + 5]);
      unsigned b1 = cvtpk(sc[kvf][base + 6], sc[kvf][base + 7]);
      unsigned ax0 = __shfl_xor(a0, 32), ax1 = __shfl_xor(a1, 32);
      unsigned bx0 = __shfl_xor(b0, 32), bx1 = __shfl_xor(b1, 32);
      union { unsigned u[4]; s16x8 s; } cv;
      cv.u[0] = hi ? bx0 : a0;
      cv.u[1] = hi ? bx1 : a1;
      cv.u[2] = hi ? b0  : ax0;
      cv.u[3] = hi ? b1  : ax1;
      pa[ks] = cv.s;
    }

    // PV (swapped): o[df] += Vt_frag * P^T_frag
    __builtin_amdgcn_s_setprio(1);
    #pragma unroll
    for (int df = 0; df < 2; df++) {
      const int vrow = df * 32 + q31;
      const int sw = (vrow & 7) << 4;
      #pragma unroll
      for (int ks = 0; ks < 4; ks++) {
        s16x8 vf = *(const s16x8*)(Vts + vrow * 128 + ((ks * 32 + hi * 16) ^ sw));
        o[df] = __builtin_amdgcn_mfma_f32_32x32x16_bf16(vf, pa[ks], o[df], 0, 0, 0);
      }
    }
    __builtin_amdgcn_s_setprio(0);
    __syncthreads();
  }

  const float inv = 1.0f / l_run;
  unsigned short* cp = ctx + ((size_t)(b * S + qrow)) * 1024 + h * 64;
  #pragma unroll
  for (int df = 0; df < 2; df++)
    #pragma unroll
    for (int rq = 0; rq < 4; rq++) {
      uint2 pw;
      pw.x = cvtpk(o[df][rq * 4 + 0] * inv, o[df][rq * 4 + 1] * inv);
      pw.y = cvtpk(o[df][rq * 4 + 2] * inv, o[df][rq * 4 + 3] * inv);
      *(uint2*)(cp + df * 32 + rq * 8 + hi * 4) = pw;
    }
}

// -------------------------------------------------------------- gemm_out ----
__global__ __launch_bounds__(256) void gemm_out_kernel(
    const unsigned short* __restrict__ Actx, const unsigned short* __restrict__ Bt,
    const float* __restrict__ bias, float* __restrict__ outp)
{
  const int tid = threadIdx.x;
  const int lane = tid & 63, w = tid >> 6;
  const int wm = w >> 1, wn = w & 1;
  const int H = blockIdx.y * 8 + blockIdx.x;
  const int L = (H & 7) * 64 + (H >> 3);
  const int m0 = (L >> 3) * 128, n0 = (L & 7) * 128;
  __shared__ __align__(16) char sA[8192];
  __shared__ __align__(16) char sB[8192];

  f32x4 acc[4][4];
  #pragma unroll
  for (int i = 0; i < 4; i++)
    #pragma unroll
    for (int j = 0; j < 4; j++)
      #pragma unroll
      for (int r = 0; r < 4; r++) acc[i][j][r] = 0.f;

  const int brow = lane >> 2;
  const int bkl  = (lane & 3) * 8;

  for (int kt = 0; kt < 32; kt++) {
    const int k0 = kt * 32;
    #pragma unroll
    for (int j = 0; j < 2; j++) {
      int row = (w * 2 + j) * 16 + brow;
      gld_lds16(Actx + (size_t)(m0 + row) * 1024 + k0 + bkl, sA + (w * 2 + j) * 1024);
      gld_lds16(Bt   + (size_t)(n0 + row) * 1024 + k0 + bkl, sB + (w * 2 + j) * 1024);
    }
    __syncthreads();
    s16x8 aF[4], bF[4];
    #pragma unroll
    for (int i = 0; i < 4; i++)
      aF[i] = *(const s16x8*)(sA + (wm * 64 + i * 16 + (lane & 15)) * 64 + (lane >> 4) * 16);
    #pragma unroll
    for (int i = 0; i < 4; i++)
      bF[i] = *(const s16x8*)(sB + (wn * 64 + i * 16 + (lane & 15)) * 64 + (lane >> 4) * 16);
    #pragma unroll
    for (int mi = 0; mi < 4; mi++)
      #pragma unroll
      for (int ni = 0; ni < 4; ni++)
        acc[mi][ni] = __builtin_amdgcn_mfma_f32_16x16x32_bf16(aF[mi], bF[ni], acc[mi][ni], 0, 0, 0);
    __syncthreads();
  }

  #pragma unroll
  for (int ni = 0; ni < 4; ni++) {
    const int gn = n0 + wn * 64 + ni * 16 + (lane & 15);
    const float bval = bias[gn];
    #pragma unroll
    for (int mi = 0; mi < 4; mi++) {
      const int gm = m0 + wm * 64 + mi * 16 + (lane >> 4) * 4;
      #pragma unroll
      for (int r = 0; r < 4; r++)
        outp[(size_t)(gm + r) * 1024 + gn] = acc[mi][ni][r] + bval;
    }
  }
}

// ---------------------------------------------------------------- launch ----
extern "C" void kernel_launch(void* const* d_in, const int* in_sizes, int n_in,
                              void* d_out, int out_size, void* d_ws, size_t ws_size,
                              hipStream_t stream)
{
  const float* query = (const float*)d_in[0];
  const float* key_  = (const float*)d_in[1];
  const float* value = (const float*)d_in[2];
  const int*   mask  = (const int*)d_in[3];
  const float* Wq = (const float*)d_in[4];
  const float* bq = (const float*)d_in[5];
  const float* Wk = (const float*)d_in[6];
  const float* bk = (const float*)d_in[7];
  const float* Wv = (const float*)d_in[8];
  const float* bv = (const float*)d_in[9];
  const float* Wo = (const float*)d_in[10];
  const float* bo = (const float*)d_in[11];
  float* out = (float*)d_out;

  // workspace layout (104 MB): ctx aliases Xb (Xb dead after gemm_qkv).
  unsigned short* Wtq = (unsigned short*)d_ws;
  unsigned short* Wtk = Wtq + (1u << 20);
  unsigned short* Wtv = Wtk + (1u << 20);
  unsigned short* Wto = Wtv + (1u << 20);
  unsigned short* Xb  = Wto + (1u << 20);   // 3 x [8192,1024] bf16 (48 MB)
  unsigned short* ctx = Xb;                 // [B,S,1024] bf16 (alias, 16 MB)
  unsigned short* Qp  = Xb  + (24u << 20);  // [B,H,S,64], pre-scaled
  unsigned short* Kp  = Qp  + (8u << 20);   // [B,H,S,64]
  unsigned short* Vtg = Kp  + (8u << 20);   // [B,H,64,S]

  wtrans_kernel<<<dim3(16, 16, 4), 256, 0, stream>>>(Wq, Wk, Wv, Wo, Wtq, Wtk, Wtv, Wto);
  a2b_kernel<<<dim3(4096, 3), 256, 0, stream>>>(query, key_, value, Xb);
  gemm_qkv_kernel<<<dim3(8, 64, 3), 256, 0, stream>>>(Xb, Wtq, Wtk, Wtv, bq, bk, bv,
                                                      Qp, Kp, Vtg);
  attn_kernel<<<dim3(16, 64), 256, 0, stream>>>(Qp, Kp, Vtg, mask, ctx);
  gemm_out_kernel<<<dim3(8, 64), 256, 0, stream>>>(ctx, Wto, bo, out);
}